// Round 4
// baseline (578.690 us; speedup 1.0000x reference)
//
#include <hip/hip_runtime.h>

constexpr int C  = 256;
constexpr int H  = 224;
constexpr int W  = 224;
constexpr int HW = H * W;               // 50176
constexpr int PIX = 64;                 // pixels per tile
constexpr int THREADS = 256;
constexpr int TILES_PER_B = HW / PIX;   // 784
constexpr int BATCH = 16;
constexpr int TILES = BATCH * TILES_PER_B;  // 12544
constexpr int GRID = 1024;              // 4 blocks/CU exactly

typedef float f32x4 __attribute__((ext_vector_type(4)));

__global__ __launch_bounds__(THREADS, 4)
void fused_sigmoid_border_scale(const float* __restrict__ x,
                                const float* __restrict__ wv,
                                const float* __restrict__ bv,
                                float* __restrict__ out)
{
    const int t    = threadIdx.x;
    const int wave = t >> 6;
    const int lane = t & 63;
    const int q    = lane & 3;    // float4 column within this wave's 16 pixels
    const int cg   = lane >> 2;   // channel subgroup 0..15

    const float b0 = bv[0];

    // Preload this lane's 16 channel weights (channels k*16+cg).
    float wk[16];
    #pragma unroll
    for (int k = 0; k < 16; ++k) wk[k] = wv[k * 16 + cg];

    for (int tile = blockIdx.x; tile < TILES; tile += GRID) {
        const int b   = tile / TILES_PER_B;
        const int hw0 = (tile - b * TILES_PER_B) * PIX;
        const int px  = hw0 + wave * 16 + q * 4;   // this lane's 4 pixels

        const float* xb = x   + (size_t)b * C * HW + px;
        float*       ob = out + (size_t)b * C * HW + px;

        // ---- load 16 channels x 4 pixels into registers (coalesced 16B) ----
        f32x4 v[16];
        #pragma unroll
        for (int k = 0; k < 16; ++k) {
            const int c = k * 16 + cg;
            v[k] = __builtin_nontemporal_load(
                reinterpret_cast<const f32x4*>(xb + (size_t)c * HW));
        }

        // ---- per-lane partial dot over its 16 channels ----
        f32x4 acc = (f32x4)(0.f);
        #pragma unroll
        for (int k = 0; k < 16; ++k) {
            acc.x = fmaf(v[k].x, wk[k], acc.x);
            acc.y = fmaf(v[k].y, wk[k], acc.y);
            acc.z = fmaf(v[k].z, wk[k], acc.z);
            acc.w = fmaf(v[k].w, wk[k], acc.w);
        }

        // ---- intra-wave reduce across the 16 cg-subgroups (bits 2..5) ----
        #pragma unroll
        for (int m = 4; m <= 32; m <<= 1) {
            acc.x += __shfl_xor(acc.x, m);
            acc.y += __shfl_xor(acc.y, m);
            acc.z += __shfl_xor(acc.z, m);
            acc.w += __shfl_xor(acc.w, m);
        }

        // ---- sigmoid + border mask for this lane's 4 pixels ----
        f32x4 comb;
        #pragma unroll
        for (int j = 0; j < 4; ++j) {
            const float s   = acc[j] + b0;
            const float att = 1.0f / (1.0f + expf(-s));
            const int hw = px + j;
            const int h  = hw / W;
            const int w  = hw - h * W;
            const bool border = (h == 0) | (h == H - 1) | (w == 0) | (w == W - 1);
            comb[j] = att * (border ? 2.0f : 1.0f);
        }

        // ---- scale and store (coalesced 16B) ----
        #pragma unroll
        for (int k = 0; k < 16; ++k) {
            const int c = k * 16 + cg;
            __builtin_nontemporal_store(v[k] * comb,
                reinterpret_cast<f32x4*>(ob + (size_t)c * HW));
        }
    }
}

extern "C" void kernel_launch(void* const* d_in, const int* in_sizes, int n_in,
                              void* d_out, int out_size, void* d_ws, size_t ws_size,
                              hipStream_t stream) {
    const float* x  = (const float*)d_in[0];
    const float* wv = (const float*)d_in[1];
    const float* bv = (const float*)d_in[2];
    float* out = (float*)d_out;

    fused_sigmoid_border_scale<<<dim3(GRID), dim3(THREADS), 0, stream>>>(x, wv, bv, out);
}

// Round 5
// 322.577 us; speedup vs baseline: 1.7940x; 1.7940x over previous
//
#include <hip/hip_runtime.h>

constexpr int C  = 256;
constexpr int H  = 224;
constexpr int W  = 224;
constexpr int HW = H * W;               // 50176
constexpr int PIX = 64;                 // pixels per block
constexpr int THREADS = 256;
constexpr int TILES_PER_B = HW / PIX;   // 784 (exact)
constexpr int BATCH = 16;

typedef float f32x4 __attribute__((ext_vector_type(4)));

__global__ __launch_bounds__(THREADS, 4)
void fused_sigmoid_border_scale(const float* __restrict__ x,
                                const float* __restrict__ wv,
                                const float* __restrict__ bv,
                                float* __restrict__ out)
{
    __shared__ f32x4 pw[4][16];    // [wave][q] partial sums, 1 KB

    const int t    = threadIdx.x;
    const int q    = t & 15;       // float4 column (pixels q*4..q*4+3)
    const int c0   = t >> 4;       // channel subgroup 0..15 (wave w covers 4w..4w+3)
    const int wave = t >> 6;
    const int blk  = blockIdx.x;
    const int b    = blk / TILES_PER_B;
    const int hw0  = (blk - b * TILES_PER_B) * PIX;

    const float* xb = x   + (size_t)b * C * HW + hw0 + q * 4;
    float*       ob = out + (size_t)b * C * HW + hw0 + q * 4;

    // ---- load tile into registers: 16 coalesced 16B loads (4x256B per wave-instr) ----
    f32x4 v[16];
    #pragma unroll
    for (int k = 0; k < 16; ++k) {
        const int c = k * 16 + c0;
        v[k] = __builtin_nontemporal_load(
            reinterpret_cast<const f32x4*>(xb + (size_t)c * HW));
    }

    // ---- per-thread partial dot over its 16 channels ----
    f32x4 acc = (f32x4)(0.f);
    #pragma unroll
    for (int k = 0; k < 16; ++k) {
        const float wk = wv[k * 16 + c0];
        acc.x = fmaf(v[k].x, wk, acc.x);
        acc.y = fmaf(v[k].y, wk, acc.y);
        acc.z = fmaf(v[k].z, wk, acc.z);
        acc.w = fmaf(v[k].w, wk, acc.w);
    }

    // Keep the loaded tile live in VGPRs — forbid load rematerialization.
    #pragma unroll
    for (int k = 0; k < 16; ++k)
        asm volatile("" : "+v"(v[k]));

    // ---- intra-wave reduce across this wave's 4 c0-subgroups (lane bits 4,5) ----
    #pragma unroll
    for (int m = 16; m <= 32; m <<= 1) {
        acc.x += __shfl_xor(acc.x, m);
        acc.y += __shfl_xor(acc.y, m);
        acc.z += __shfl_xor(acc.z, m);
        acc.w += __shfl_xor(acc.w, m);
    }
    if ((t & 63) < 16) pw[wave][q] = acc;   // one f32x4 per q per wave
    __syncthreads();                        // the ONLY barrier

    // ---- every thread: combine 4 wave-partials + sigmoid + border for its 4 px ----
    const f32x4 s4 = pw[0][q] + pw[1][q] + pw[2][q] + pw[3][q];
    const float b0 = bv[0];
    f32x4 comb;
    #pragma unroll
    for (int j = 0; j < 4; ++j) {
        const float att = 1.0f / (1.0f + expf(-(s4[j] + b0)));
        const int hw = hw0 + q * 4 + j;
        const int h  = hw / W;
        const int w  = hw - h * W;
        const bool border = (h == 0) | (h == H - 1) | (w == 0) | (w == W - 1);
        comb[j] = att * (border ? 2.0f : 1.0f);
    }

    // ---- scale registers and store, coalesced 16B stores ----
    #pragma unroll
    for (int k = 0; k < 16; ++k) {
        const int c = k * 16 + c0;
        __builtin_nontemporal_store(v[k] * comb,
            reinterpret_cast<f32x4*>(ob + (size_t)c * HW));
    }
}

extern "C" void kernel_launch(void* const* d_in, const int* in_sizes, int n_in,
                              void* d_out, int out_size, void* d_ws, size_t ws_size,
                              hipStream_t stream) {
    const float* x  = (const float*)d_in[0];
    const float* wv = (const float*)d_in[1];
    const float* bv = (const float*)d_in[2];
    float* out = (float*)d_out;

    dim3 grid(BATCH * TILES_PER_B);   // 12544 blocks, one 64-pixel tile each
    fused_sigmoid_border_scale<<<grid, THREADS, 0, stream>>>(x, wv, bv, out);
}